// Round 4
// baseline (111.039 us; speedup 1.0000x reference)
//
#include <hip/hip_runtime.h>
#include <math.h>

#define CAPV 2560

__device__ __forceinline__ float wave_sum64(float v) {
#pragma unroll
  for (int o = 32; o; o >>= 1) v += __shfl_xor(v, o, 64);
  return v;
}

__device__ __forceinline__ float silu_f(float t) {
  return t * __builtin_amdgcn_rcpf(1.f + __expf(-t));
}

// ---------------- routing + weight transpose: 17 blocks ----------------
// block 0: gate computation for all 256 patches + stem weight transpose
// blocks 1..16: transpose expert (l,e) weights to [ci][co*9+k] (72 contiguous
//               floats per ci-slice -> wave-uniform s_load in token kernel)
__global__ __launch_bounds__(256) void routing_kernel(
    const float* __restrict__ gate_w, const float* __restrict__ gate_b,
    const float* __restrict__ stem_w, const float* __restrict__ exp_w,
    int* __restrict__ route_e, float* __restrict__ route_gate,
    int* __restrict__ route_cpre, int* __restrict__ route_Ce,
    float* __restrict__ stemT, float* __restrict__ wT,
    float* __restrict__ d_scalars) {
  const int tid = threadIdx.x;
  if (blockIdx.x > 0) {
    int le = blockIdx.x - 1;
    for (int i = tid; i < 576; i += 256) {
      int ci = i / 72, r2 = i % 72;
      int co = r2 / 9, k = r2 % 9;
      wT[le * 576 + i] = exp_w[((le * 8 + co) * 8 + ci) * 9 + k];
    }
    return;
  }
  // stemT[ci*72 + co*9 + k] = stem_w[(co*3+ci)*9 + k]
  if (tid < 216) {
    int ci = tid / 72, r2 = tid % 72;
    int co = r2 / 9, k = r2 % 9;
    stemT[tid] = stem_w[(co * 3 + ci) * 9 + k];
  }

  const int p = tid;                    // patch index 0..255
  const int lane = p & 63, wv = p >> 6; // 4 waves
  const int hp = p >> 4, wp = p & 15;

  // pooled fourier features (mean over 8x8 patch)
  float pool[18];
  {
    float my = 0.f, mx_ = 0.f;
    float msy[4] = {0, 0, 0, 0}, mcy[4] = {0, 0, 0, 0};
    float msx[4] = {0, 0, 0, 0}, mcx[4] = {0, 0, 0, 0};
#pragma unroll
    for (int r = 0; r < 8; ++r) {
      float yv = -1.f + (2.f / 127.f) * (float)(hp * 8 + r);
      float xv = -1.f + (2.f / 127.f) * (float)(wp * 8 + r);
      my += yv; mx_ += xv;
#pragma unroll
      for (int k = 0; k < 4; ++k) {
        float fr = 3.14159265358979323846f * (float)(1 << k);
        msy[k] += sinf(fr * yv); mcy[k] += cosf(fr * yv);
        msx[k] += sinf(fr * xv); mcx[k] += cosf(fr * xv);
      }
    }
    pool[0] = my * 0.125f; pool[1] = mx_ * 0.125f;
#pragma unroll
    for (int k = 0; k < 4; ++k) {
      pool[2 + 4 * k] = msy[k] * 0.125f;
      pool[3 + 4 * k] = mcy[k] * 0.125f;
      pool[4 + 4 * k] = msx[k] * 0.125f;
      pool[5 + 4 * k] = mcx[k] * 0.125f;
    }
  }

  __shared__ float sWP[4][8];
  __shared__ float sWZ[4];
  __shared__ int sWCnt[4][8];
  __shared__ float sMeanP[8], sFrac[8];
  __shared__ float sAcc[2];
  if (p == 0) { sAcc[0] = 0.f; sAcc[1] = 0.f; }

  for (int l = 0; l < 2; ++l) {
    float logit[8];
#pragma unroll
    for (int e = 0; e < 8; ++e) logit[e] = gate_b[l * 8 + e];
#pragma unroll
    for (int c = 0; c < 18; ++c) {
      float pl = pool[c];
#pragma unroll
      for (int e = 0; e < 8; ++e)
        logit[e] = fmaf(pl, gate_w[(l * 18 + c) * 8 + e], logit[e]);
    }
    float mxv = logit[0]; int em = 0;
#pragma unroll
    for (int e = 1; e < 8; ++e)
      if (logit[e] > mxv) { mxv = logit[e]; em = e; }
    float pr[8]; float se = 0.f;
#pragma unroll
    for (int e = 0; e < 8; ++e) { pr[e] = expf(logit[e] - mxv); se += pr[e]; }
    float inv = 1.f / se;
#pragma unroll
    for (int e = 0; e < 8; ++e) pr[e] *= inv;
    float lse = mxv + logf(se);
    float gate_val = inv;

    unsigned long long meq[8];
#pragma unroll
    for (int e = 0; e < 8; ++e) meq[e] = __ballot(em == e);
    unsigned long long mm = meq[0];
#pragma unroll
    for (int e = 1; e < 8; ++e) mm = (em == e) ? meq[e] : mm;
    unsigned long long below = (2ull << lane) - 1ull;
    int cpre_w = (int)__popcll(mm & below);
    if (lane < 8) {
      unsigned long long t = meq[0];
#pragma unroll
      for (int e = 1; e < 8; ++e) t = (lane == e) ? meq[e] : t;
      sWCnt[wv][lane] = (int)__popcll(t);
    }
    float z2 = wave_sum64(lse * lse);
    if (lane == 0) sWZ[wv] = z2;
#pragma unroll
    for (int e = 0; e < 8; ++e) {
      float s = wave_sum64(pr[e]);
      if (lane == 0) sWP[wv][e] = s;
    }
    __syncthreads();

    int cpre = cpre_w;
#pragma unroll
    for (int w2 = 0; w2 < 4; ++w2)
      if (w2 < wv) cpre += sWCnt[w2][em];

    route_e[l * 256 + p] = em;
    route_gate[l * 256 + p] = gate_val;
    route_cpre[l * 256 + p] = cpre;

    if (p < 8) {
      int ce = sWCnt[0][p] + sWCnt[1][p] + sWCnt[2][p] + sWCnt[3][p];
      route_Ce[l * 8 + p] = ce;
      int kept = 0;
      for (int bb = 0; bb < 64; ++bb) {
        int r = CAPV - bb * ce;
        r = r < 0 ? 0 : r;
        kept += (r < ce ? r : ce);
      }
      sFrac[p] = (float)kept * (1.f / 16384.f);
      sMeanP[p] = (sWP[0][p] + sWP[1][p] + sWP[2][p] + sWP[3][p]) * (1.f / 256.f);
    }
    __syncthreads();
    if (p == 0) {
      float s = 0.f;
#pragma unroll
      for (int e = 0; e < 8; ++e) s += sMeanP[e] * sFrac[e];
      sAcc[1] += 8.f * s;
      sAcc[0] += (sWZ[0] + sWZ[1] + sWZ[2] + sWZ[3]) * (1.f / 256.f);
    }
    __syncthreads();
  }
  if (p == 0) { d_scalars[0] = sAcc[0]; d_scalars[1] = sAcc[1]; }
}

// ------- token kernel: 4 tokens / block, lane = pixel (y,x), SGPR weights -------
__global__ __launch_bounds__(256) void token_kernel(
    const float* __restrict__ X,
    const float* __restrict__ stemT, const float* __restrict__ stem_sc,
    const float* __restrict__ stem_bi,
    const float* __restrict__ wT, const float* __restrict__ exp_b,
    const float* __restrict__ gn_s, const float* __restrict__ gn_b,
    const int* __restrict__ route_e, const float* __restrict__ route_gate,
    const int* __restrict__ route_cpre, const int* __restrict__ route_Ce,
    float* __restrict__ blk_sums) {
  const int g = blockIdx.x;
  const int b = g >> 6, r6 = g & 63;
  const int hp = r6 >> 2, wq = r6 & 3;      // 4 horizontally adjacent patches
  const int tid = threadIdx.x;
  const int w = tid >> 6, lane = tid & 63;  // wave == token
  const int y = lane >> 3, x = lane & 7;    // lane = pixel
  const int p = hp * 16 + wq * 4 + w;

  __shared__ __align__(16) float sX[3][10][36];    // shared halo
  __shared__ __align__(16) float sT[4][8][10][12]; // stride-12 rows: 2-way-free banks
  __shared__ float sRed[4][12];

  // zero own token buffer entirely (960 floats = 240 float4); interior is
  // overwritten by stem; only the border ring must survive as zero.
  {
    float4 z = {0.f, 0.f, 0.f, 0.f};
    float4* t4 = (float4*)&sT[w][0][0][0];
#pragma unroll
    for (int i = 0; i < 4; ++i) {
      int idx = lane + i * 64;
      if (idx < 240) t4[idx] = z;
    }
  }

  // cooperative coalesced halo load: 3 x 10 x 34 region
  const int gy0 = hp * 8 - 1, gx0 = wq * 32 - 1;
#pragma unroll
  for (int k = 0; k < 4; ++k) {
    int i = tid + k * 256;
    if (i < 1020) {
      int ci = i / 340, rem = i - ci * 340;
      int r = rem / 34, c = rem - r * 34;
      int gy = gy0 + r, gx = gx0 + c;
      float v = 0.f;
      if (gy >= 0 && gy < 128 && gx >= 0 && gx < 128)
        v = X[((b * 3 + ci) * 128 + gy) * 128 + gx];
      sX[ci][r][c] = v;
    }
  }
  __syncthreads();

  const int cx = w * 8 + x;  // sX column for dx=0

  // ---- stem: each lane computes its pixel, all 8 channels; weights in SGPR ----
  {
    float acc[8];
#pragma unroll
    for (int co = 0; co < 8; ++co) acc[co] = 0.f;
#pragma unroll
    for (int ci = 0; ci < 3; ++ci) {
      float win[9];
#pragma unroll
      for (int dy = 0; dy < 3; ++dy)
#pragma unroll
        for (int dx = 0; dx < 3; ++dx)
          win[dy * 3 + dx] = sX[ci][y + dy][cx + dx];
      const float* wp = stemT + ci * 72;  // wave-uniform -> s_load
#pragma unroll
      for (int co = 0; co < 8; ++co)
#pragma unroll
        for (int k = 0; k < 9; ++k)
          acc[co] = fmaf(wp[co * 9 + k], win[k], acc[co]);
    }
#pragma unroll
    for (int co = 0; co < 8; ++co) {
      float t = fmaf(acc[co], stem_sc[co], stem_bi[co]);
      sT[w][co][y + 1][x + 1] = silu_f(t);
    }
  }
  // sT[w] is wave-private; wave-ordered DS suffices (no barrier needed).

  float a[8];
#pragma unroll
  for (int l = 0; l < 2; ++l) {
    int e = __builtin_amdgcn_readfirstlane(route_e[l * 256 + p]);
    float gp = route_gate[l * 256 + p];
    int cpre = route_cpre[l * 256 + p];
    int Ce = route_Ce[l * 8 + e];
    float gate = (b * Ce + cpre <= CAPV) ? gp : 0.f;
    const int le = l * 8 + e;
    const float* __restrict__ wbase = wT + le * 576;  // wave-uniform

#pragma unroll
    for (int co = 0; co < 8; ++co) a[co] = exp_b[le * 8 + co];
#pragma unroll
    for (int ci = 0; ci < 8; ++ci) {
      float win[9];
#pragma unroll
      for (int dy = 0; dy < 3; ++dy)
#pragma unroll
        for (int dx = 0; dx < 3; ++dx)
          win[dy * 3 + dx] = sT[w][ci][y + dy][x + dx];
      const float* wp = wbase + ci * 72;  // wave-uniform -> s_load
#pragma unroll
      for (int co = 0; co < 8; ++co)
#pragma unroll
        for (int k = 0; k < 9; ++k)
          a[co] = fmaf(wp[co * 9 + k], win[k], a[co]);
    }
#pragma unroll
    for (int co = 0; co < 8; ++co) a[co] = silu_f(a[co]) * gate;

    if (l == 0) {
      // per-token GroupNorm: 4 groups of (2 ch x 64 px); all lanes hold all ch
      float s4v[4], q4v[4];
#pragma unroll
      for (int g4 = 0; g4 < 4; ++g4) {
        s4v[g4] = a[2 * g4] + a[2 * g4 + 1];
        q4v[g4] = a[2 * g4] * a[2 * g4] + a[2 * g4 + 1] * a[2 * g4 + 1];
      }
#pragma unroll
      for (int g4 = 0; g4 < 4; ++g4) {
        s4v[g4] = wave_sum64(s4v[g4]);
        q4v[g4] = wave_sum64(q4v[g4]);
      }
#pragma unroll
      for (int co = 0; co < 8; ++co) {
        int g4 = co >> 1;
        float mu = s4v[g4] * (1.f / 128.f);
        float var = q4v[g4] * (1.f / 128.f) - mu * mu;
        float inv = rsqrtf(var + 1e-5f);
        float sc2 = inv * gn_s[co];
        float bi2 = fmaf(-mu, sc2, gn_b[co]);
        sT[w][co][y + 1][x + 1] = fmaf(a[co], sc2, bi2);
      }
    }
  }

  // per-token partials: 8 channel sums + 4 group sum-of-squares
  {
    float s8[8], q4v[4];
#pragma unroll
    for (int c = 0; c < 8; ++c) s8[c] = a[c];
#pragma unroll
    for (int g4 = 0; g4 < 4; ++g4)
      q4v[g4] = a[2 * g4] * a[2 * g4] + a[2 * g4 + 1] * a[2 * g4 + 1];
#pragma unroll
    for (int c = 0; c < 8; ++c) s8[c] = wave_sum64(s8[c]);
#pragma unroll
    for (int g4 = 0; g4 < 4; ++g4) q4v[g4] = wave_sum64(q4v[g4]);
    if (lane == 0) {
#pragma unroll
      for (int c = 0; c < 8; ++c) sRed[w][c] = s8[c];
#pragma unroll
      for (int g4 = 0; g4 < 4; ++g4) sRed[w][8 + g4] = q4v[g4];
    }
  }
  __syncthreads();
  if (tid < 12)
    blk_sums[(size_t)g * 12 + tid] =
        sRed[0][tid] + sRed[1][tid] + sRed[2][tid] + sRed[3][tid];
}

// ---------------- finish: per-image GN-folded pooling + MLP head ----------------
__global__ __launch_bounds__(64) void finish_kernel(
    const float* __restrict__ blk_sums,
    const float* __restrict__ gn_s, const float* __restrict__ gn_b,
    const float* __restrict__ w1, const float* __restrict__ b1,
    const float* __restrict__ w2, const float* __restrict__ b2,
    float* __restrict__ out) {
  const int b = blockIdx.x;
  const int lane = threadIdx.x;

  const float4* s4 = (const float4*)(blk_sums + (size_t)(b * 64 + lane) * 12);
  float4 a0 = s4[0], a1 = s4[1], a2 = s4[2];
  float l0[12] = {a0.x, a0.y, a0.z, a0.w, a1.x, a1.y, a1.z, a1.w,
                  a2.x, a2.y, a2.z, a2.w};
#pragma unroll
  for (int j = 0; j < 12; ++j) l0[j] = wave_sum64(l0[j]);

  float pooled[8];
#pragma unroll
  for (int c = 0; c < 8; ++c) {
    int gg = c >> 1;
    float mean_c = l0[c] * (1.f / 16384.f);
    float mug = (l0[2 * gg] + l0[2 * gg + 1]) * (1.f / 32768.f);
    float var = l0[8 + gg] * (1.f / 32768.f) - mug * mug;
    pooled[c] = fmaf((mean_c - mug) * rsqrtf(var + 1e-5f), gn_s[8 + c], gn_b[8 + c]);
  }

  __shared__ float sH1[32];
  if (lane < 32) {
    float h = b1[lane];
#pragma unroll
    for (int c = 0; c < 8; ++c) h = fmaf(pooled[c], w1[c * 32 + lane], h);
    float t = 0.7978845608028654f * fmaf(0.044715f * h * h, h, h);
    sH1[lane] = 0.5f * h * (1.f + tanhf(t));
  }
  __syncthreads();
  for (int o = lane; o < 100; o += 64) {
    float v = b2[o];
#pragma unroll
    for (int j = 0; j < 32; ++j) v = fmaf(sH1[j], w2[j * 100 + o], v);
    out[b * 100 + o] = v;
  }
}

extern "C" void kernel_launch(void* const* d_in, const int* in_sizes, int n_in,
                              void* d_out, int out_size, void* d_ws, size_t ws_size,
                              hipStream_t stream) {
  const float* X       = (const float*)d_in[0];
  const float* stem_w  = (const float*)d_in[1];
  const float* stem_sc = (const float*)d_in[2];
  const float* stem_bi = (const float*)d_in[3];
  const float* gate_w  = (const float*)d_in[4];
  const float* gate_b  = (const float*)d_in[5];
  const float* exp_w   = (const float*)d_in[6];
  const float* exp_b   = (const float*)d_in[7];
  const float* gn_s    = (const float*)d_in[8];
  const float* gn_b    = (const float*)d_in[9];
  const float* w1      = (const float*)d_in[10];
  const float* b1      = (const float*)d_in[11];
  const float* w2      = (const float*)d_in[12];
  const float* b2      = (const float*)d_in[13];
  float* out = (float*)d_out;

  char* ws = (char*)d_ws;
  int* route_e      = (int*)(ws + 0);            // 512 ints
  int* route_cpre   = (int*)(ws + 2048);         // 512 ints
  int* route_Ce     = (int*)(ws + 4096);         // 16 ints
  float* route_gate = (float*)(ws + 4160);       // 512 floats
  float* stemT      = (float*)(ws + 8192);       // 216 floats
  float* wT         = (float*)(ws + 16384);      // 9216 floats (36 KiB)
  float* blk_sums   = (float*)(ws + 65536);      // 4096*12 floats (192 KiB)

  routing_kernel<<<17, 256, 0, stream>>>(gate_w, gate_b, stem_w, exp_w,
                                         route_e, route_gate, route_cpre,
                                         route_Ce, stemT, wT, out + 6400);
  token_kernel<<<4096, 256, 0, stream>>>(X, stemT, stem_sc, stem_bi, wT,
                                         exp_b, gn_s, gn_b, route_e, route_gate,
                                         route_cpre, route_Ce, blk_sums);
  finish_kernel<<<64, 64, 0, stream>>>(blk_sums, gn_s, gn_b, w1, b1, w2, b2,
                                       out);
}

// Round 5
// 74.967 us; speedup vs baseline: 1.4812x; 1.4812x over previous
//
#include <hip/hip_runtime.h>
#include <math.h>

#define CAPV 2560

__device__ __forceinline__ float wave_sum64(float v) {
#pragma unroll
  for (int o = 32; o; o >>= 1) v += __shfl_xor(v, o, 64);
  return v;
}

__device__ __forceinline__ float silu_f(float t) {
  return t * __builtin_amdgcn_rcpf(1.f + __expf(-t));
}

// ---------------- routing + weight transpose: 17 blocks ----------------
// block 0: gates for all 256 patches (trig via shared table) + stem transpose
// blocks 1..16: transpose expert (l,e) weights into [ci][co][12]-padded layout
__global__ __launch_bounds__(256) void routing_kernel(
    const float* __restrict__ gate_w, const float* __restrict__ gate_b,
    const float* __restrict__ stem_w, const float* __restrict__ exp_w,
    int* __restrict__ route_e, float* __restrict__ route_gate,
    int* __restrict__ route_cpre, int* __restrict__ route_Ce,
    float* __restrict__ stemT2, float* __restrict__ wT2,
    float* __restrict__ d_scalars) {
  const int tid = threadIdx.x;
  if (blockIdx.x > 0) {
    int le = blockIdx.x - 1;
    for (int i = tid; i < 576; i += 256) {
      int co = i / 72, r2 = i % 72;
      int ci = r2 / 9, t = r2 % 9;
      // wT2[((le*8+ci)*8+co)*12 + t] = exp_w[le*576 + (co*8+ci)*9 + t]
      wT2[((le * 8 + ci) * 8 + co) * 12 + t] = exp_w[le * 576 + i];
    }
    return;
  }
  // stemT2[(ci*8+co)*12 + t] = stem_w[(co*3+ci)*9 + t]
  if (tid < 216) {
    int co = tid / 27, r2 = tid % 27;
    int ci = r2 / 9, t = r2 % 9;
    stemT2[(ci * 8 + co) * 12 + t] = stem_w[tid];
  }

  // ---- trig table: 128 rows x 4 freqs (same table serves y and x) ----
  __shared__ float tS[128][4], tC[128][4];
  __shared__ float sS8[16][4], sC8[16][4];  // per-8-row means
  if (tid < 128) {
    float yv = -1.f + (2.f / 127.f) * (float)tid;
#pragma unroll
    for (int k = 0; k < 4; ++k) {
      float fr = 3.14159265358979323846f * (float)(1 << k);
      tS[tid][k] = sinf(fr * yv);
      tC[tid][k] = cosf(fr * yv);
    }
  }
  __syncthreads();
  if (tid < 64) {
    int g8 = tid >> 2, k = tid & 3;
    float s = 0.f, c = 0.f;
#pragma unroll
    for (int r = 0; r < 8; ++r) {
      s += tS[g8 * 8 + r][k];
      c += tC[g8 * 8 + r][k];
    }
    sS8[g8][k] = s * 0.125f;
    sC8[g8][k] = c * 0.125f;
  }
  __syncthreads();

  const int p = tid;                    // patch index 0..255
  const int lane = p & 63, wv = p >> 6; // 4 waves
  const int hp = p >> 4, wp = p & 15;

  float pool[18];
  pool[0] = -1.f + (2.f / 127.f) * ((float)(hp * 8) + 3.5f);
  pool[1] = -1.f + (2.f / 127.f) * ((float)(wp * 8) + 3.5f);
#pragma unroll
  for (int k = 0; k < 4; ++k) {
    pool[2 + 4 * k] = sS8[hp][k];
    pool[3 + 4 * k] = sC8[hp][k];
    pool[4 + 4 * k] = sS8[wp][k];
    pool[5 + 4 * k] = sC8[wp][k];
  }

  __shared__ float sWP[4][8];
  __shared__ float sWZ[4];
  __shared__ int sWCnt[4][8];
  __shared__ float sMeanP[8], sFrac[8];
  __shared__ float sAcc[2];
  if (p == 0) { sAcc[0] = 0.f; sAcc[1] = 0.f; }

  for (int l = 0; l < 2; ++l) {
    float logit[8];
#pragma unroll
    for (int e = 0; e < 8; ++e) logit[e] = gate_b[l * 8 + e];
#pragma unroll
    for (int c = 0; c < 18; ++c) {
      float pl = pool[c];
#pragma unroll
      for (int e = 0; e < 8; ++e)
        logit[e] = fmaf(pl, gate_w[(l * 18 + c) * 8 + e], logit[e]);
    }
    float mxv = logit[0]; int em = 0;
#pragma unroll
    for (int e = 1; e < 8; ++e)
      if (logit[e] > mxv) { mxv = logit[e]; em = e; }
    float pr[8]; float se = 0.f;
#pragma unroll
    for (int e = 0; e < 8; ++e) { pr[e] = expf(logit[e] - mxv); se += pr[e]; }
    float inv = 1.f / se;
#pragma unroll
    for (int e = 0; e < 8; ++e) pr[e] *= inv;
    float lse = mxv + logf(se);
    float gate_val = inv;

    unsigned long long meq[8];
#pragma unroll
    for (int e = 0; e < 8; ++e) meq[e] = __ballot(em == e);
    unsigned long long mm = meq[0];
#pragma unroll
    for (int e = 1; e < 8; ++e) mm = (em == e) ? meq[e] : mm;
    unsigned long long below = (2ull << lane) - 1ull;
    int cpre_w = (int)__popcll(mm & below);
    if (lane < 8) {
      unsigned long long t = meq[0];
#pragma unroll
      for (int e = 1; e < 8; ++e) t = (lane == e) ? meq[e] : t;
      sWCnt[wv][lane] = (int)__popcll(t);
    }
    float z2 = wave_sum64(lse * lse);
    if (lane == 0) sWZ[wv] = z2;
#pragma unroll
    for (int e = 0; e < 8; ++e) {
      float s = wave_sum64(pr[e]);
      if (lane == 0) sWP[wv][e] = s;
    }
    __syncthreads();

    int cpre = cpre_w;
#pragma unroll
    for (int w2 = 0; w2 < 4; ++w2)
      if (w2 < wv) cpre += sWCnt[w2][em];

    route_e[l * 256 + p] = em;
    route_gate[l * 256 + p] = gate_val;
    route_cpre[l * 256 + p] = cpre;

    if (p < 8) {
      int ce = sWCnt[0][p] + sWCnt[1][p] + sWCnt[2][p] + sWCnt[3][p];
      route_Ce[l * 8 + p] = ce;
      int kept = 0;
      for (int bb = 0; bb < 64; ++bb) {
        int r = CAPV - bb * ce;
        r = r < 0 ? 0 : r;
        kept += (r < ce ? r : ce);
      }
      sFrac[p] = (float)kept * (1.f / 16384.f);
      sMeanP[p] = (sWP[0][p] + sWP[1][p] + sWP[2][p] + sWP[3][p]) * (1.f / 256.f);
    }
    __syncthreads();
    if (p == 0) {
      float s = 0.f;
#pragma unroll
      for (int e = 0; e < 8; ++e) s += sMeanP[e] * sFrac[e];
      sAcc[1] += 8.f * s;
      sAcc[0] += (sWZ[0] + sWZ[1] + sWZ[2] + sWZ[3]) * (1.f / 256.f);
    }
    __syncthreads();
  }
  if (p == 0) { d_scalars[0] = sAcc[0]; d_scalars[1] = sAcc[1]; }
}

// ---------------- token kernel: 4 tokens / block, lane = (y, co) ----------------
__global__ __launch_bounds__(256, 6) void token_kernel(
    const float* __restrict__ X,
    const float* __restrict__ stemT2, const float* __restrict__ stem_sc,
    const float* __restrict__ stem_bi,
    const float* __restrict__ wT2, const float* __restrict__ exp_b,
    const float* __restrict__ gn_s, const float* __restrict__ gn_b,
    const int* __restrict__ route_e, const float* __restrict__ route_gate,
    const int* __restrict__ route_cpre, const int* __restrict__ route_Ce,
    float* __restrict__ blk_sums) {
  const int g = blockIdx.x;
  const int b = g >> 6, r6 = g & 63;
  const int hp = r6 >> 2, wq = r6 & 3;      // 4 horizontally adjacent patches
  const int tid = threadIdx.x;
  const int w = tid >> 6, lane = tid & 63;  // wave == token
  const int y = lane >> 3, co = lane & 7;   // lane = output row x channel
  const int p = hp * 16 + wq * 4 + w;
  const int xb = w * 8;

  __shared__ __align__(16) float sX[3][10][36];     // shared halo
  __shared__ __align__(16) float sT[4][8][10][12];  // stride-12 rows
  __shared__ float sRed[4][12];

  // zero border rows 0 and 9 of own token; interior rows fully written by stem
  if (lane < 48) {
    int q = lane % 3, rr = (lane / 3) & 1, ch = lane / 6;
    float4 z = {0.f, 0.f, 0.f, 0.f};
    *(float4*)&sT[w][ch][rr * 9][q * 4] = z;
  }

  // cooperative coalesced halo load: 3 x 10 x 34 region
  const int gy0 = hp * 8 - 1, gx0 = wq * 32 - 1;
#pragma unroll
  for (int k = 0; k < 4; ++k) {
    int i = tid + k * 256;
    if (i < 1020) {
      int ci = i / 340, rem = i - ci * 340;
      int r = rem / 34, c = rem - r * 34;
      int gy = gy0 + r, gx = gx0 + c;
      float v = 0.f;
      if (gy >= 0 && gy < 128 && gx >= 0 && gx < 128)
        v = X[((b * 3 + ci) * 128 + gy) * 128 + gx];
      sX[ci][r][c] = v;
    }
  }
  __syncthreads();

  // ---- stem: lane computes row y, channel co, 8 pixels ----
  {
    float acc[8];
#pragma unroll
    for (int px = 0; px < 8; ++px) acc[px] = 0.f;
#pragma unroll
    for (int ci = 0; ci < 3; ++ci) {
      float r[3][10];
#pragma unroll
      for (int dy = 0; dy < 3; ++dy) {
        const float* rp = &sX[ci][y + dy][xb];
        float4 q0 = *(const float4*)rp;
        float4 q1 = *(const float4*)(rp + 4);
        float2 q2 = *(const float2*)(rp + 8);
        r[dy][0] = q0.x; r[dy][1] = q0.y; r[dy][2] = q0.z; r[dy][3] = q0.w;
        r[dy][4] = q1.x; r[dy][5] = q1.y; r[dy][6] = q1.z; r[dy][7] = q1.w;
        r[dy][8] = q2.x; r[dy][9] = q2.y;
      }
      const float* wp = stemT2 + (ci * 8 + co) * 12;
      float4 wa = *(const float4*)wp;
      float4 wbv = *(const float4*)(wp + 4);
      float w8 = wp[8];
      float ws9[9] = {wa.x, wa.y, wa.z, wa.w, wbv.x, wbv.y, wbv.z, wbv.w, w8};
#pragma unroll
      for (int dy = 0; dy < 3; ++dy)
#pragma unroll
        for (int dx = 0; dx < 3; ++dx) {
          float wv = ws9[dy * 3 + dx];
#pragma unroll
          for (int px = 0; px < 8; ++px)
            acc[px] = fmaf(wv, r[dy][px + dx], acc[px]);
        }
    }
    float sc = stem_sc[co], bi = stem_bi[co];
    float s0 = silu_f(fmaf(acc[0], sc, bi));
    float s1 = silu_f(fmaf(acc[1], sc, bi));
    float s2 = silu_f(fmaf(acc[2], sc, bi));
    float s3 = silu_f(fmaf(acc[3], sc, bi));
    float s4 = silu_f(fmaf(acc[4], sc, bi));
    float s5 = silu_f(fmaf(acc[5], sc, bi));
    float s6 = silu_f(fmaf(acc[6], sc, bi));
    float s7 = silu_f(fmaf(acc[7], sc, bi));
    float* dst = &sT[w][co][y + 1][0];
    float4 o0 = {0.f, s0, s1, s2};
    float4 o1 = {s3, s4, s5, s6};
    float4 o2 = {s7, 0.f, 0.f, 0.f};
    *(float4*)dst = o0;
    *(float4*)(dst + 4) = o1;
    *(float4*)(dst + 8) = o2;
  }
  // sT[w] is wave-private; wave-ordered DS suffices (no barrier).

  float a[8];
#pragma unroll
  for (int l = 0; l < 2; ++l) {
    int e = __builtin_amdgcn_readfirstlane(route_e[l * 256 + p]);
    float gp = route_gate[l * 256 + p];
    int cpre = route_cpre[l * 256 + p];
    int Ce = route_Ce[l * 8 + e];
    float gate = (b * Ce + cpre <= CAPV) ? gp : 0.f;
    const int le = l * 8 + e;

#pragma unroll
    for (int px = 0; px < 8; ++px) a[px] = 0.f;
#pragma unroll
    for (int ci = 0; ci < 8; ++ci) {
      float r[3][10];
#pragma unroll
      for (int dy = 0; dy < 3; ++dy) {
        const float* rp = &sT[w][ci][y + dy][0];
        float4 q0 = *(const float4*)rp;
        float4 q1 = *(const float4*)(rp + 4);
        float2 q2 = *(const float2*)(rp + 8);
        r[dy][0] = q0.x; r[dy][1] = q0.y; r[dy][2] = q0.z; r[dy][3] = q0.w;
        r[dy][4] = q1.x; r[dy][5] = q1.y; r[dy][6] = q1.z; r[dy][7] = q1.w;
        r[dy][8] = q2.x; r[dy][9] = q2.y;
      }
      const float* wp = wT2 + ((le * 8 + ci) * 8 + co) * 12;
      float4 wa = *(const float4*)wp;
      float4 wbv = *(const float4*)(wp + 4);
      float w8 = wp[8];
      float ws9[9] = {wa.x, wa.y, wa.z, wa.w, wbv.x, wbv.y, wbv.z, wbv.w, w8};
#pragma unroll
      for (int dy = 0; dy < 3; ++dy)
#pragma unroll
        for (int dx = 0; dx < 3; ++dx) {
          float wv = ws9[dy * 3 + dx];
#pragma unroll
          for (int px = 0; px < 8; ++px)
            a[px] = fmaf(wv, r[dy][px + dx], a[px]);
        }
    }
    float bias = exp_b[le * 8 + co];
#pragma unroll
    for (int px = 0; px < 8; ++px) a[px] = silu_f(a[px] + bias) * gate;

    if (l == 0) {
      // per-token GroupNorm: groups = channel pairs; reduce over bit0(co), bits3-5(y)
      float s = 0.f, q = 0.f;
#pragma unroll
      for (int px = 0; px < 8; ++px) { s += a[px]; q += a[px] * a[px]; }
      s += __shfl_xor(s, 1, 64);  q += __shfl_xor(q, 1, 64);
      s += __shfl_xor(s, 8, 64);  q += __shfl_xor(q, 8, 64);
      s += __shfl_xor(s, 16, 64); q += __shfl_xor(q, 16, 64);
      s += __shfl_xor(s, 32, 64); q += __shfl_xor(q, 32, 64);
      float mu = s * (1.f / 128.f);
      float var = q * (1.f / 128.f) - mu * mu;
      float inv = rsqrtf(var + 1e-5f);
      float sc2 = inv * gn_s[co];
      float bi2 = fmaf(-mu, sc2, gn_b[co]);
      float n0 = fmaf(a[0], sc2, bi2), n1 = fmaf(a[1], sc2, bi2);
      float n2 = fmaf(a[2], sc2, bi2), n3 = fmaf(a[3], sc2, bi2);
      float n4 = fmaf(a[4], sc2, bi2), n5 = fmaf(a[5], sc2, bi2);
      float n6 = fmaf(a[6], sc2, bi2), n7 = fmaf(a[7], sc2, bi2);
      float* dst = &sT[w][co][y + 1][0];
      float4 o0 = {0.f, n0, n1, n2};
      float4 o1 = {n3, n4, n5, n6};
      float4 o2 = {n7, 0.f, 0.f, 0.f};
      *(float4*)dst = o0;
      *(float4*)(dst + 4) = o1;
      *(float4*)(dst + 8) = o2;
    }
  }

  // final per-token partials: channel sums (8) + group sum-of-squares (4)
  {
    float s = 0.f, q = 0.f;
#pragma unroll
    for (int px = 0; px < 8; ++px) { s += a[px]; q += a[px] * a[px]; }
    s += __shfl_xor(s, 8, 64);
    s += __shfl_xor(s, 16, 64);
    s += __shfl_xor(s, 32, 64);
    q += __shfl_xor(q, 1, 64);
    q += __shfl_xor(q, 8, 64);
    q += __shfl_xor(q, 16, 64);
    q += __shfl_xor(q, 32, 64);
    if (lane < 8) sRed[w][lane] = s;
    if (lane < 8 && !(lane & 1)) sRed[w][8 + (lane >> 1)] = q;
  }
  __syncthreads();
  if (tid < 12)
    blk_sums[(size_t)g * 12 + tid] =
        sRed[0][tid] + sRed[1][tid] + sRed[2][tid] + sRed[3][tid];
}

// ---------------- finish: per-image GN-folded pooling + MLP head ----------------
__global__ __launch_bounds__(64) void finish_kernel(
    const float* __restrict__ blk_sums,
    const float* __restrict__ gn_s, const float* __restrict__ gn_b,
    const float* __restrict__ w1, const float* __restrict__ b1,
    const float* __restrict__ w2, const float* __restrict__ b2,
    float* __restrict__ out) {
  const int b = blockIdx.x;
  const int lane = threadIdx.x;

  const float4* s4 = (const float4*)(blk_sums + (size_t)(b * 64 + lane) * 12);
  float4 a0 = s4[0], a1 = s4[1], a2 = s4[2];
  float l0[12] = {a0.x, a0.y, a0.z, a0.w, a1.x, a1.y, a1.z, a1.w,
                  a2.x, a2.y, a2.z, a2.w};
#pragma unroll
  for (int j = 0; j < 12; ++j) l0[j] = wave_sum64(l0[j]);

  float pooled[8];
#pragma unroll
  for (int c = 0; c < 8; ++c) {
    int gg = c >> 1;
    float mean_c = l0[c] * (1.f / 16384.f);
    float mug = (l0[2 * gg] + l0[2 * gg + 1]) * (1.f / 32768.f);
    float var = l0[8 + gg] * (1.f / 32768.f) - mug * mug;
    pooled[c] = fmaf((mean_c - mug) * rsqrtf(var + 1e-5f), gn_s[8 + c], gn_b[8 + c]);
  }

  __shared__ float sH1[32];
  if (lane < 32) {
    float h = b1[lane];
#pragma unroll
    for (int c = 0; c < 8; ++c) h = fmaf(pooled[c], w1[c * 32 + lane], h);
    float t = 0.7978845608028654f * fmaf(0.044715f * h * h, h, h);
    sH1[lane] = 0.5f * h * (1.f + tanhf(t));
  }
  __syncthreads();
  for (int o = lane; o < 100; o += 64) {
    float v = b2[o];
#pragma unroll
    for (int j = 0; j < 32; ++j) v = fmaf(sH1[j], w2[j * 100 + o], v);
    out[b * 100 + o] = v;
  }
}

extern "C" void kernel_launch(void* const* d_in, const int* in_sizes, int n_in,
                              void* d_out, int out_size, void* d_ws, size_t ws_size,
                              hipStream_t stream) {
  const float* X       = (const float*)d_in[0];
  const float* stem_w  = (const float*)d_in[1];
  const float* stem_sc = (const float*)d_in[2];
  const float* stem_bi = (const float*)d_in[3];
  const float* gate_w  = (const float*)d_in[4];
  const float* gate_b  = (const float*)d_in[5];
  const float* exp_w   = (const float*)d_in[6];
  const float* exp_b   = (const float*)d_in[7];
  const float* gn_s    = (const float*)d_in[8];
  const float* gn_b    = (const float*)d_in[9];
  const float* w1      = (const float*)d_in[10];
  const float* b1      = (const float*)d_in[11];
  const float* w2      = (const float*)d_in[12];
  const float* b2      = (const float*)d_in[13];
  float* out = (float*)d_out;

  char* ws = (char*)d_ws;
  int* route_e      = (int*)(ws + 0);            // 512 ints
  int* route_cpre   = (int*)(ws + 2048);         // 512 ints
  int* route_Ce     = (int*)(ws + 4096);         // 16 ints
  float* route_gate = (float*)(ws + 4160);       // 512 floats
  float* stemT2     = (float*)(ws + 8192);       // 288 floats
  float* wT2        = (float*)(ws + 16384);      // 12288 floats (48 KiB)
  float* blk_sums   = (float*)(ws + 65536);      // 4096*12 floats (192 KiB)

  routing_kernel<<<17, 256, 0, stream>>>(gate_w, gate_b, stem_w, exp_w,
                                         route_e, route_gate, route_cpre,
                                         route_Ce, stemT2, wT2, out + 6400);
  token_kernel<<<4096, 256, 0, stream>>>(X, stemT2, stem_sc, stem_bi, wT2,
                                         exp_b, gn_s, gn_b, route_e, route_gate,
                                         route_cpre, route_Ce, blk_sums);
  finish_kernel<<<64, 64, 0, stream>>>(blk_sums, gn_s, gn_b, w1, b1, w2, b2,
                                       out);
}

// Round 6
// 51.886 us; speedup vs baseline: 2.1401x; 1.4448x over previous
//
#include <hip/hip_runtime.h>
#include <math.h>

#define CAPV 2560

typedef __bf16 bf16x8 __attribute__((ext_vector_type(8)));
typedef float f32x4 __attribute__((ext_vector_type(4)));

__device__ __forceinline__ float wave_sum64(float v) {
#pragma unroll
  for (int o = 32; o; o >>= 1) v += __shfl_xor(v, o, 64);
  return v;
}

__device__ __forceinline__ float silu_f(float t) {
  return t * __builtin_amdgcn_rcpf(1.f + __expf(-t));
}

__device__ __forceinline__ unsigned short f2bf(float f) {
  unsigned u = __float_as_uint(f);
  return (unsigned short)((u + 0x7FFFu + ((u >> 16) & 1u)) >> 16);
}

// ---------------- routing + weight packing: 17 blocks ----------------
// block 0: gates for all 256 patches (trig via shared table) + stem transpose
// blocks 1..16: pack expert (le) weights into MFMA B-fragment layout, bf16:
//   expPack[le][chunk c][lane][j] ; k = c*32+(lane>>4)*8+j ; col = lane&15
//   k -> tap = k>>3 (dy=tap>>2, dx=tap&3, dx==3 is a zero pad slot), ci = k&7
__global__ __launch_bounds__(256) void routing_kernel(
    const float* __restrict__ gate_w, const float* __restrict__ gate_b,
    const float* __restrict__ stem_w, const float* __restrict__ exp_w,
    int* __restrict__ route_e, float* __restrict__ route_gate,
    int* __restrict__ route_cpre, int* __restrict__ route_Ce,
    float* __restrict__ stemT2, unsigned short* __restrict__ expPack,
    float* __restrict__ d_scalars) {
  const int tid = threadIdx.x;
  if (blockIdx.x > 0) {
    int le = blockIdx.x - 1;
    for (int i = tid; i < 1536; i += 256) {
      int c = i >> 9, rem = i & 511, ln = rem >> 3, j = rem & 7;
      int k = c * 32 + ((ln >> 4) << 3) + j;
      int cl = ln & 15;
      int tap = k >> 3, ci = k & 7;
      int dy = tap >> 2, dx = tap & 3;
      float v = 0.f;
      if (cl < 8 && dx < 3)
        v = exp_w[((le * 8 + cl) * 8 + ci) * 9 + dy * 3 + dx];
      expPack[le * 1536 + i] = f2bf(v);
    }
    return;
  }
  // stemT2[(ci*8+co)*12 + t] = stem_w[(co*3+ci)*9 + t]  (fp32, padded rows)
  if (tid < 216) {
    int co = tid / 27, r2 = tid % 27;
    int ci = r2 / 9, t = r2 % 9;
    stemT2[(ci * 8 + co) * 12 + t] = stem_w[tid];
  }

  // ---- trig table: 128 rows x 4 freqs (same table serves y and x) ----
  __shared__ float tS[128][4], tC[128][4];
  __shared__ float sS8[16][4], sC8[16][4];
  if (tid < 128) {
    float yv = -1.f + (2.f / 127.f) * (float)tid;
#pragma unroll
    for (int k = 0; k < 4; ++k) {
      float fr = 3.14159265358979323846f * (float)(1 << k);
      tS[tid][k] = sinf(fr * yv);
      tC[tid][k] = cosf(fr * yv);
    }
  }
  __syncthreads();
  if (tid < 64) {
    int g8 = tid >> 2, k = tid & 3;
    float s = 0.f, c = 0.f;
#pragma unroll
    for (int r = 0; r < 8; ++r) {
      s += tS[g8 * 8 + r][k];
      c += tC[g8 * 8 + r][k];
    }
    sS8[g8][k] = s * 0.125f;
    sC8[g8][k] = c * 0.125f;
  }
  __syncthreads();

  const int p = tid;
  const int lane = p & 63, wv = p >> 6;
  const int hp = p >> 4, wp = p & 15;

  float pool[18];
  pool[0] = -1.f + (2.f / 127.f) * ((float)(hp * 8) + 3.5f);
  pool[1] = -1.f + (2.f / 127.f) * ((float)(wp * 8) + 3.5f);
#pragma unroll
  for (int k = 0; k < 4; ++k) {
    pool[2 + 4 * k] = sS8[hp][k];
    pool[3 + 4 * k] = sC8[hp][k];
    pool[4 + 4 * k] = sS8[wp][k];
    pool[5 + 4 * k] = sC8[wp][k];
  }

  __shared__ float sWP[4][8];
  __shared__ float sWZ[4];
  __shared__ int sWCnt[4][8];
  __shared__ float sMeanP[8], sFrac[8];
  __shared__ float sAcc[2];
  if (p == 0) { sAcc[0] = 0.f; sAcc[1] = 0.f; }

  for (int l = 0; l < 2; ++l) {
    float logit[8];
#pragma unroll
    for (int e = 0; e < 8; ++e) logit[e] = gate_b[l * 8 + e];
#pragma unroll
    for (int c = 0; c < 18; ++c) {
      float pl = pool[c];
#pragma unroll
      for (int e = 0; e < 8; ++e)
        logit[e] = fmaf(pl, gate_w[(l * 18 + c) * 8 + e], logit[e]);
    }
    float mxv = logit[0]; int em = 0;
#pragma unroll
    for (int e = 1; e < 8; ++e)
      if (logit[e] > mxv) { mxv = logit[e]; em = e; }
    float pr[8]; float se = 0.f;
#pragma unroll
    for (int e = 0; e < 8; ++e) { pr[e] = expf(logit[e] - mxv); se += pr[e]; }
    float inv = 1.f / se;
#pragma unroll
    for (int e = 0; e < 8; ++e) pr[e] *= inv;
    float lse = mxv + logf(se);
    float gate_val = inv;

    unsigned long long meq[8];
#pragma unroll
    for (int e = 0; e < 8; ++e) meq[e] = __ballot(em == e);
    unsigned long long mm = meq[0];
#pragma unroll
    for (int e = 1; e < 8; ++e) mm = (em == e) ? meq[e] : mm;
    unsigned long long below = (2ull << lane) - 1ull;
    int cpre_w = (int)__popcll(mm & below);
    if (lane < 8) {
      unsigned long long t = meq[0];
#pragma unroll
      for (int e = 1; e < 8; ++e) t = (lane == e) ? meq[e] : t;
      sWCnt[wv][lane] = (int)__popcll(t);
    }
    float z2 = wave_sum64(lse * lse);
    if (lane == 0) sWZ[wv] = z2;
#pragma unroll
    for (int e = 0; e < 8; ++e) {
      float s = wave_sum64(pr[e]);
      if (lane == 0) sWP[wv][e] = s;
    }
    __syncthreads();

    int cpre = cpre_w;
#pragma unroll
    for (int w2 = 0; w2 < 4; ++w2)
      if (w2 < wv) cpre += sWCnt[w2][em];

    route_e[l * 256 + p] = em;
    route_gate[l * 256 + p] = gate_val;
    route_cpre[l * 256 + p] = cpre;

    if (p < 8) {
      int ce = sWCnt[0][p] + sWCnt[1][p] + sWCnt[2][p] + sWCnt[3][p];
      route_Ce[l * 8 + p] = ce;
      int kept = 0;
      for (int bb = 0; bb < 64; ++bb) {
        int r = CAPV - bb * ce;
        r = r < 0 ? 0 : r;
        kept += (r < ce ? r : ce);
      }
      sFrac[p] = (float)kept * (1.f / 16384.f);
      sMeanP[p] = (sWP[0][p] + sWP[1][p] + sWP[2][p] + sWP[3][p]) * (1.f / 256.f);
    }
    __syncthreads();
    if (p == 0) {
      float s = 0.f;
#pragma unroll
      for (int e = 0; e < 8; ++e) s += sMeanP[e] * sFrac[e];
      sAcc[1] += 8.f * s;
      sAcc[0] += (sWZ[0] + sWZ[1] + sWZ[2] + sWZ[3]) * (1.f / 256.f);
    }
    __syncthreads();
  }
  if (p == 0) { d_scalars[0] = sAcc[0]; d_scalars[1] = sAcc[1]; }
}

// ------- token kernel: 4 tokens/block; stem VALU fp32, expert convs MFMA bf16 -------
__global__ __launch_bounds__(256) void token_kernel(
    const float* __restrict__ X,
    const float* __restrict__ stemT2, const float* __restrict__ stem_sc,
    const float* __restrict__ stem_bi,
    const unsigned short* __restrict__ expPack, const float* __restrict__ exp_b,
    const float* __restrict__ gn_s, const float* __restrict__ gn_b,
    const int* __restrict__ route_e, const float* __restrict__ route_gate,
    const int* __restrict__ route_cpre, const int* __restrict__ route_Ce,
    float* __restrict__ blk_sums) {
  const int g = blockIdx.x;
  const int b = g >> 6, r6 = g & 63;
  const int hp = r6 >> 2, wq = r6 & 3;      // 4 horizontally adjacent patches
  const int tid = threadIdx.x;
  const int w = tid >> 6, lane = tid & 63;  // wave == token
  const int p = hp * 16 + wq * 4 + w;

  __shared__ __align__(16) float sX[3][10][36];          // fp32 halo (4 patches)
  __shared__ __align__(16) unsigned short sT[4][10][12][8]; // bf16 ch-last, padded
  __shared__ float sRed[4][12];

  // ---- routing data + B-fragment prefetch for both layers ----
  const int e0 = __builtin_amdgcn_readfirstlane(route_e[p]);
  const int e1 = __builtin_amdgcn_readfirstlane(route_e[256 + p]);
  const float gp0 = route_gate[p], gp1 = route_gate[256 + p];
  const int cp0 = route_cpre[p], cp1 = route_cpre[256 + p];
  const int Ce0 = route_Ce[e0], Ce1 = route_Ce[8 + e1];
  const float gate0 = (b * Ce0 + cp0 <= CAPV) ? gp0 : 0.f;
  const float gate1 = (b * Ce1 + cp1 <= CAPV) ? gp1 : 0.f;
  const int le0 = e0, le1 = 8 + e1;
  const bf16x8* bp0 = (const bf16x8*)(expPack + le0 * 1536);
  const bf16x8* bp1 = (const bf16x8*)(expPack + le1 * 1536);
  bf16x8 B00 = bp0[lane], B01 = bp0[64 + lane], B02 = bp0[128 + lane];
  bf16x8 B10 = bp1[lane], B11 = bp1[64 + lane], B12 = bp1[128 + lane];

  // ---- zero border ring + pad cols of own token (56 16B cells) ----
  if (lane < 56) {
    int row, col;
    if (lane < 12) { row = 0; col = lane; }
    else if (lane < 24) { row = 9; col = lane - 12; }
    else { int q = lane - 24; row = 1 + (q >> 2); int m = q & 3; col = (m == 0) ? 0 : 8 + m; }
    int4 z = {0, 0, 0, 0};
    *(int4*)&sT[w][row][col][0] = z;
  }

  // ---- cooperative coalesced halo load: 3 x 10 x 34 fp32 ----
  const int gy0 = hp * 8 - 1, gx0 = wq * 32 - 1;
#pragma unroll
  for (int k = 0; k < 4; ++k) {
    int i = tid + k * 256;
    if (i < 1020) {
      int ci = i / 340, rem = i - ci * 340;
      int r = rem / 34, c = rem - r * 34;
      int gy = gy0 + r, gx = gx0 + c;
      float v = 0.f;
      if (gy >= 0 && gy < 128 && gx >= 0 && gx < 128)
        v = X[((b * 3 + ci) * 128 + gy) * 128 + gx];
      sX[ci][r][c] = v;
    }
  }
  __syncthreads();

  // ---- stem (fp32 VALU, proven R2 structure): lane = (row sy, channel sco) ----
  {
    const int sy = lane >> 3, sco = lane & 7;
    const int xb = w * 8;
    float acc[8];
#pragma unroll
    for (int px = 0; px < 8; ++px) acc[px] = 0.f;
#pragma unroll
    for (int ci = 0; ci < 3; ++ci) {
      float r[3][10];
#pragma unroll
      for (int dy = 0; dy < 3; ++dy) {
        const float* rp = &sX[ci][sy + dy][xb];
        float4 q0 = *(const float4*)rp;
        float4 q1 = *(const float4*)(rp + 4);
        float2 q2 = *(const float2*)(rp + 8);
        r[dy][0] = q0.x; r[dy][1] = q0.y; r[dy][2] = q0.z; r[dy][3] = q0.w;
        r[dy][4] = q1.x; r[dy][5] = q1.y; r[dy][6] = q1.z; r[dy][7] = q1.w;
        r[dy][8] = q2.x; r[dy][9] = q2.y;
      }
      const float* wp = stemT2 + (ci * 8 + sco) * 12;
      float4 wa = *(const float4*)wp;
      float4 wbv = *(const float4*)(wp + 4);
      float w8 = wp[8];
      float ws9[9] = {wa.x, wa.y, wa.z, wa.w, wbv.x, wbv.y, wbv.z, wbv.w, w8};
#pragma unroll
      for (int dy = 0; dy < 3; ++dy)
#pragma unroll
        for (int dx = 0; dx < 3; ++dx) {
          float wv = ws9[dy * 3 + dx];
#pragma unroll
          for (int px = 0; px < 8; ++px)
            acc[px] = fmaf(wv, r[dy][px + dx], acc[px]);
        }
    }
    float sc = stem_sc[sco], bi = stem_bi[sco];
#pragma unroll
    for (int px = 0; px < 8; ++px) {
      float t = silu_f(fmaf(acc[px], sc, bi));
      sT[w][sy + 1][px + 1][sco] = f2bf(t);  // bf16 ch-last scatter
    }
  }
  // sT[w] is wave-private; in-wave DS ordering suffices (no barrier).

  // ---- expert layers via MFMA: A row = px (l&15 within rowgroup), k-grp = l>>4 ----
  const int col = lane & 15;       // output channel (valid < 8)
  const int gq = lane >> 4;        // k-quadrant / D row-group-of-4
  const int ay = (lane & 15) >> 3; // A: px>>3 within rowgroup
  const int ax = lane & 7;         // A: px&7
  // A base: sT[w][ay + (rg*2 + c)][ax + gq][0]; rg -> +384B, c -> +192B
  const unsigned short* abase = &sT[w][ay][ax + gq][0];
  const float sgs0 = gn_s[col & 7], sgb0 = gn_b[col & 7];
  const float bias0 = exp_b[le0 * 8 + (col & 7)];
  const float bias1 = exp_b[le1 * 8 + (col & 7)];

  // D px mapping: px = rg*16 + gq*4 + r -> y = rg*2 + (gq>>1), x = (gq&1)*4 + r
  const int dy_ = (gq >> 1) + 1, dx_ = (gq & 1) * 4 + 1;

  float v1s, v1q;  // layer-1 per-lane partials
  {
    // ---------- layer 0 ----------
    f32x4 a0 = {0.f, 0.f, 0.f, 0.f}, a1 = a0, a2 = a0, a3 = a0;
#pragma unroll
    for (int c = 0; c < 3; ++c) {
      const bf16x8 A0 = *(const bf16x8*)(abase + (c * 2 + 0) * 96);
      const bf16x8 A1 = *(const bf16x8*)(abase + (c * 2 + 2) * 96 - c * 96);
      // offsets: rg*192 + c*96 shorts; write explicitly:
      const bf16x8 Ar0 = *(const bf16x8*)(abase + (0 * 192 + c * 96));
      const bf16x8 Ar1 = *(const bf16x8*)(abase + (1 * 192 + c * 96));
      const bf16x8 Ar2 = *(const bf16x8*)(abase + (2 * 192 + c * 96));
      const bf16x8 Ar3 = *(const bf16x8*)(abase + (3 * 192 + c * 96));
      const bf16x8 Bc = (c == 0) ? B00 : (c == 1) ? B01 : B02;
      a0 = __builtin_amdgcn_mfma_f32_16x16x32_bf16(Ar0, Bc, a0, 0, 0, 0);
      a1 = __builtin_amdgcn_mfma_f32_16x16x32_bf16(Ar1, Bc, a1, 0, 0, 0);
      a2 = __builtin_amdgcn_mfma_f32_16x16x32_bf16(Ar2, Bc, a2, 0, 0, 0);
      a3 = __builtin_amdgcn_mfma_f32_16x16x32_bf16(Ar3, Bc, a3, 0, 0, 0);
      (void)A0; (void)A1;
    }
    // epilogue: bias + silu + gate, GroupNorm (pairs of channels), write bf16
    float v[16];
    float s = 0.f, q = 0.f;
#pragma unroll
    for (int rg = 0; rg < 4; ++rg) {
      f32x4 ar = (rg == 0) ? a0 : (rg == 1) ? a1 : (rg == 2) ? a2 : a3;
#pragma unroll
      for (int r = 0; r < 4; ++r) {
        float t = silu_f(ar[r] + bias0) * gate0;
        v[rg * 4 + r] = t;
        s += t;
        q += t * t;
      }
    }
    s += __shfl_xor(s, 16, 64); q += __shfl_xor(q, 16, 64);
    s += __shfl_xor(s, 32, 64); q += __shfl_xor(q, 32, 64);
    s += __shfl_xor(s, 1, 64);  q += __shfl_xor(q, 1, 64);
    float mu = s * (1.f / 128.f);
    float var = q * (1.f / 128.f) - mu * mu;
    float inv = rsqrtf(var + 1e-5f);
    float sc2 = inv * sgs0;
    float bi2 = fmaf(-mu, sc2, sgb0);
    if (col < 8) {
#pragma unroll
      for (int rg = 0; rg < 4; ++rg)
#pragma unroll
        for (int r = 0; r < 4; ++r) {
          float n = fmaf(v[rg * 4 + r], sc2, bi2);
          sT[w][rg * 2 + dy_][dx_ + r][col] = f2bf(n);
        }
    }
  }
  {
    // ---------- layer 1 ----------
    f32x4 a0 = {0.f, 0.f, 0.f, 0.f}, a1 = a0, a2 = a0, a3 = a0;
#pragma unroll
    for (int c = 0; c < 3; ++c) {
      const bf16x8 Ar0 = *(const bf16x8*)(abase + (0 * 192 + c * 96));
      const bf16x8 Ar1 = *(const bf16x8*)(abase + (1 * 192 + c * 96));
      const bf16x8 Ar2 = *(const bf16x8*)(abase + (2 * 192 + c * 96));
      const bf16x8 Ar3 = *(const bf16x8*)(abase + (3 * 192 + c * 96));
      const bf16x8 Bc = (c == 0) ? B10 : (c == 1) ? B11 : B12;
      a0 = __builtin_amdgcn_mfma_f32_16x16x32_bf16(Ar0, Bc, a0, 0, 0, 0);
      a1 = __builtin_amdgcn_mfma_f32_16x16x32_bf16(Ar1, Bc, a1, 0, 0, 0);
      a2 = __builtin_amdgcn_mfma_f32_16x16x32_bf16(Ar2, Bc, a2, 0, 0, 0);
      a3 = __builtin_amdgcn_mfma_f32_16x16x32_bf16(Ar3, Bc, a3, 0, 0, 0);
    }
    float s = 0.f, q = 0.f;
#pragma unroll
    for (int rg = 0; rg < 4; ++rg) {
      f32x4 ar = (rg == 0) ? a0 : (rg == 1) ? a1 : (rg == 2) ? a2 : a3;
#pragma unroll
      for (int r = 0; r < 4; ++r) {
        float t = silu_f(ar[r] + bias1) * gate1;
        s += t;
        q += t * t;
      }
    }
    s += __shfl_xor(s, 16, 64); q += __shfl_xor(q, 16, 64);
    s += __shfl_xor(s, 32, 64); q += __shfl_xor(q, 32, 64);
    v1s = s;
    v1q = q + __shfl_xor(q, 1, 64);
  }

  if (lane < 8) sRed[w][lane] = v1s;                       // col==lane, gq==0
  if (lane < 8 && !(lane & 1)) sRed[w][8 + (lane >> 1)] = v1q;
  __syncthreads();
  if (tid < 12)
    blk_sums[(size_t)g * 12 + tid] =
        sRed[0][tid] + sRed[1][tid] + sRed[2][tid] + sRed[3][tid];
}

// ---------------- finish: per-image GN-folded pooling + MLP head ----------------
__global__ __launch_bounds__(64) void finish_kernel(
    const float* __restrict__ blk_sums,
    const float* __restrict__ gn_s, const float* __restrict__ gn_b,
    const float* __restrict__ w1, const float* __restrict__ b1,
    const float* __restrict__ w2, const float* __restrict__ b2,
    float* __restrict__ out) {
  const int b = blockIdx.x;
  const int lane = threadIdx.x;

  const float4* s4 = (const float4*)(blk_sums + (size_t)(b * 64 + lane) * 12);
  float4 a0 = s4[0], a1 = s4[1], a2 = s4[2];
  float l0[12] = {a0.x, a0.y, a0.z, a0.w, a1.x, a1.y, a1.z, a1.w,
                  a2.x, a2.y, a2.z, a2.w};
#pragma unroll
  for (int j = 0; j < 12; ++j) l0[j] = wave_sum64(l0[j]);

  float pooled[8];
#pragma unroll
  for (int c = 0; c < 8; ++c) {
    int gg = c >> 1;
    float mean_c = l0[c] * (1.f / 16384.f);
    float mug = (l0[2 * gg] + l0[2 * gg + 1]) * (1.f / 32768.f);
    float var = l0[8 + gg] * (1.f / 32768.f) - mug * mug;
    pooled[c] = fmaf((mean_c - mug) * rsqrtf(var + 1e-5f), gn_s[8 + c], gn_b[8 + c]);
  }

  __shared__ float sH1[32];
  if (lane < 32) {
    float h = b1[lane];
#pragma unroll
    for (int c = 0; c < 8; ++c) h = fmaf(pooled[c], w1[c * 32 + lane], h);
    float t = 0.7978845608028654f * fmaf(0.044715f * h * h, h, h);
    sH1[lane] = 0.5f * h * (1.f + tanhf(t));
  }
  __syncthreads();
  for (int o = lane; o < 100; o += 64) {
    float v = b2[o];
#pragma unroll
    for (int j = 0; j < 32; ++j) v = fmaf(sH1[j], w2[j * 100 + o], v);
    out[b * 100 + o] = v;
  }
}

extern "C" void kernel_launch(void* const* d_in, const int* in_sizes, int n_in,
                              void* d_out, int out_size, void* d_ws, size_t ws_size,
                              hipStream_t stream) {
  const float* X       = (const float*)d_in[0];
  const float* stem_w  = (const float*)d_in[1];
  const float* stem_sc = (const float*)d_in[2];
  const float* stem_bi = (const float*)d_in[3];
  const float* gate_w  = (const float*)d_in[4];
  const float* gate_b  = (const float*)d_in[5];
  const float* exp_w   = (const float*)d_in[6];
  const float* exp_b   = (const float*)d_in[7];
  const float* gn_s    = (const float*)d_in[8];
  const float* gn_b    = (const float*)d_in[9];
  const float* w1      = (const float*)d_in[10];
  const float* b1      = (const float*)d_in[11];
  const float* w2      = (const float*)d_in[12];
  const float* b2      = (const float*)d_in[13];
  float* out = (float*)d_out;

  char* ws = (char*)d_ws;
  int* route_e             = (int*)(ws + 0);        // 512 ints
  int* route_cpre          = (int*)(ws + 2048);     // 512 ints
  int* route_Ce            = (int*)(ws + 4096);     // 16 ints
  float* route_gate        = (float*)(ws + 4160);   // 512 floats
  float* stemT2            = (float*)(ws + 8192);   // 288 floats
  unsigned short* expPack  = (unsigned short*)(ws + 16384);  // 16*1536 bf16 (48 KiB)
  float* blk_sums          = (float*)(ws + 65536);  // 4096*12 floats (192 KiB)

  routing_kernel<<<17, 256, 0, stream>>>(gate_w, gate_b, stem_w, exp_w,
                                         route_e, route_gate, route_cpre,
                                         route_Ce, stemT2, expPack, out + 6400);
  token_kernel<<<4096, 256, 0, stream>>>(X, stemT2, stem_sc, stem_bi, expPack,
                                         exp_b, gn_s, gn_b, route_e, route_gate,
                                         route_cpre, route_Ce, blk_sums);
  finish_kernel<<<64, 64, 0, stream>>>(blk_sums, gn_s, gn_b, w1, b1, w2, b2,
                                       out);
}

// Round 7
// 51.124 us; speedup vs baseline: 2.1720x; 1.0149x over previous
//
#include <hip/hip_runtime.h>
#include <math.h>

#define CAPV 2560

typedef __bf16 bf16x8 __attribute__((ext_vector_type(8)));
typedef float f32x4 __attribute__((ext_vector_type(4)));

__device__ __forceinline__ float wave_sum64(float v) {
#pragma unroll
  for (int o = 32; o; o >>= 1) v += __shfl_xor(v, o, 64);
  return v;
}

__device__ __forceinline__ float silu_f(float t) {
  return t * __builtin_amdgcn_rcpf(1.f + __expf(-t));
}

// ---------------- routing + weight packing: 17 blocks ----------------
// MFMA B-fragment layout (16x16x32 bf16): col = lane&15, k = c*32+(lane>>4)*8+j
//   k -> tap = k>>3 (dy = tap>>2, dx = tap&3; dx==3 is a zero pad slot), ci = k&7
// block 0: gates for all 256 patches + stem pack (ci 3..7 zero, BN scale folded)
// blocks 1..16: expert (le) pack
__global__ __launch_bounds__(256) void routing_kernel(
    const float* __restrict__ gate_w, const float* __restrict__ gate_b,
    const float* __restrict__ stem_w, const float* __restrict__ stem_sc,
    const float* __restrict__ exp_w,
    int* __restrict__ route_e, float* __restrict__ route_gate,
    int* __restrict__ route_cpre, int* __restrict__ route_Ce,
    __bf16* __restrict__ stemPack, __bf16* __restrict__ expPack,
    float* __restrict__ d_scalars) {
  const int tid = threadIdx.x;
  if (blockIdx.x > 0) {
    int le = blockIdx.x - 1;
    for (int i = tid; i < 1536; i += 256) {
      int c = i >> 9, rem = i & 511, ln = rem >> 3, j = rem & 7;
      int k = c * 32 + ((ln >> 4) << 3) + j;
      int cl = ln & 15;
      int tap = k >> 3, ci = k & 7;
      int dy = tap >> 2, dx = tap & 3;
      float v = 0.f;
      if (cl < 8 && dx < 3)
        v = exp_w[((le * 8 + cl) * 8 + ci) * 9 + dy * 3 + dx];
      expPack[le * 1536 + i] = (__bf16)v;
    }
    return;
  }
  // stem pack: same fragment layout, ci limited to 0..2, scale folded in
  for (int i = tid; i < 1536; i += 256) {
    int c = i >> 9, rem = i & 511, ln = rem >> 3, j = rem & 7;
    int k = c * 32 + ((ln >> 4) << 3) + j;
    int cl = ln & 15;
    int tap = k >> 3, ci = k & 7;
    int dy = tap >> 2, dx = tap & 3;
    float v = 0.f;
    if (cl < 8 && dx < 3 && ci < 3)
      v = stem_w[(cl * 3 + ci) * 9 + dy * 3 + dx] * stem_sc[cl];
    stemPack[i] = (__bf16)v;
  }

  // ---- trig table: 128 rows x 4 freqs (same table serves y and x) ----
  __shared__ float tS[128][4], tC[128][4];
  __shared__ float sS8[16][4], sC8[16][4];
  if (tid < 128) {
    float yv = -1.f + (2.f / 127.f) * (float)tid;
#pragma unroll
    for (int k = 0; k < 4; ++k) {
      float fr = 3.14159265358979323846f * (float)(1 << k);
      tS[tid][k] = sinf(fr * yv);
      tC[tid][k] = cosf(fr * yv);
    }
  }
  __syncthreads();
  if (tid < 64) {
    int g8 = tid >> 2, k = tid & 3;
    float s = 0.f, c = 0.f;
#pragma unroll
    for (int r = 0; r < 8; ++r) {
      s += tS[g8 * 8 + r][k];
      c += tC[g8 * 8 + r][k];
    }
    sS8[g8][k] = s * 0.125f;
    sC8[g8][k] = c * 0.125f;
  }
  __syncthreads();

  const int p = tid;
  const int lane = p & 63, wv = p >> 6;
  const int hp = p >> 4, wp = p & 15;

  float pool[18];
  pool[0] = -1.f + (2.f / 127.f) * ((float)(hp * 8) + 3.5f);
  pool[1] = -1.f + (2.f / 127.f) * ((float)(wp * 8) + 3.5f);
#pragma unroll
  for (int k = 0; k < 4; ++k) {
    pool[2 + 4 * k] = sS8[hp][k];
    pool[3 + 4 * k] = sC8[hp][k];
    pool[4 + 4 * k] = sS8[wp][k];
    pool[5 + 4 * k] = sC8[wp][k];
  }

  __shared__ float sWP[4][8];
  __shared__ float sWZ[4];
  __shared__ int sWCnt[4][8];
  __shared__ float sMeanP[8], sFrac[8];
  __shared__ float sAcc[2];
  if (p == 0) { sAcc[0] = 0.f; sAcc[1] = 0.f; }

  for (int l = 0; l < 2; ++l) {
    float logit[8];
#pragma unroll
    for (int e = 0; e < 8; ++e) logit[e] = gate_b[l * 8 + e];
#pragma unroll
    for (int c = 0; c < 18; ++c) {
      float pl = pool[c];
#pragma unroll
      for (int e = 0; e < 8; ++e)
        logit[e] = fmaf(pl, gate_w[(l * 18 + c) * 8 + e], logit[e]);
    }
    float mxv = logit[0]; int em = 0;
#pragma unroll
    for (int e = 1; e < 8; ++e)
      if (logit[e] > mxv) { mxv = logit[e]; em = e; }
    float pr[8]; float se = 0.f;
#pragma unroll
    for (int e = 0; e < 8; ++e) { pr[e] = expf(logit[e] - mxv); se += pr[e]; }
    float inv = 1.f / se;
#pragma unroll
    for (int e = 0; e < 8; ++e) pr[e] *= inv;
    float lse = mxv + logf(se);
    float gate_val = inv;

    unsigned long long meq[8];
#pragma unroll
    for (int e = 0; e < 8; ++e) meq[e] = __ballot(em == e);
    unsigned long long mm = meq[0];
#pragma unroll
    for (int e = 1; e < 8; ++e) mm = (em == e) ? meq[e] : mm;
    unsigned long long below = (2ull << lane) - 1ull;
    int cpre_w = (int)__popcll(mm & below);
    if (lane < 8) {
      unsigned long long t = meq[0];
#pragma unroll
      for (int e = 1; e < 8; ++e) t = (lane == e) ? meq[e] : t;
      sWCnt[wv][lane] = (int)__popcll(t);
    }
    float z2 = wave_sum64(lse * lse);
    if (lane == 0) sWZ[wv] = z2;
#pragma unroll
    for (int e = 0; e < 8; ++e) {
      float s = wave_sum64(pr[e]);
      if (lane == 0) sWP[wv][e] = s;
    }
    __syncthreads();

    int cpre = cpre_w;
#pragma unroll
    for (int w2 = 0; w2 < 4; ++w2)
      if (w2 < wv) cpre += sWCnt[w2][em];

    route_e[l * 256 + p] = em;
    route_gate[l * 256 + p] = gate_val;
    route_cpre[l * 256 + p] = cpre;

    if (p < 8) {
      int ce = sWCnt[0][p] + sWCnt[1][p] + sWCnt[2][p] + sWCnt[3][p];
      route_Ce[l * 8 + p] = ce;
      int kept = 0;
      for (int bb = 0; bb < 64; ++bb) {
        int r = CAPV - bb * ce;
        r = r < 0 ? 0 : r;
        kept += (r < ce ? r : ce);
      }
      sFrac[p] = (float)kept * (1.f / 16384.f);
      sMeanP[p] = (sWP[0][p] + sWP[1][p] + sWP[2][p] + sWP[3][p]) * (1.f / 256.f);
    }
    __syncthreads();
    if (p == 0) {
      float s = 0.f;
#pragma unroll
      for (int e = 0; e < 8; ++e) s += sMeanP[e] * sFrac[e];
      sAcc[1] += 8.f * s;
      sAcc[0] += (sWZ[0] + sWZ[1] + sWZ[2] + sWZ[3]) * (1.f / 256.f);
    }
    __syncthreads();
  }
  if (p == 0) { d_scalars[0] = sAcc[0]; d_scalars[1] = sAcc[1]; }
}

// ------- token kernel: 4 tokens/block; stem AND expert convs via MFMA bf16 -------
__global__ __launch_bounds__(256) void token_kernel(
    const float* __restrict__ X,
    const __bf16* __restrict__ stemPack, const float* __restrict__ stem_bi,
    const __bf16* __restrict__ expPack, const float* __restrict__ exp_b,
    const float* __restrict__ gn_s, const float* __restrict__ gn_b,
    const int* __restrict__ route_e, const float* __restrict__ route_gate,
    const int* __restrict__ route_cpre, const int* __restrict__ route_Ce,
    float* __restrict__ blk_sums) {
  const int g = blockIdx.x;
  const int b = g >> 6, r6 = g & 63;
  const int hp = r6 >> 2, wq = r6 & 3;      // 4 horizontally adjacent patches
  const int tid = threadIdx.x;
  const int w = tid >> 6, lane = tid & 63;  // wave == token
  const int p = hp * 16 + wq * 4 + w;

  // MFMA lane decomposition (shared by stem + both expert layers)
  const int col = lane & 15;       // output channel (valid < 8)
  const int gq = lane >> 4;        // k-quadrant / D row-group-of-4
  const int ay = (lane & 15) >> 3; // A: px>>3 within rowgroup
  const int ax = lane & 7;         // A: px&7
  const int dy_ = (gq >> 1) + 1, dx_ = (gq & 1) * 4 + 1;  // D -> (y,x) mapping

  __shared__ __align__(16) __bf16 sH[10][36][8];     // bf16 halo, ch-last (ci 0..2)
  __shared__ __align__(16) __bf16 sT[4][10][12][8];  // bf16 token buf, ch-last
  __shared__ float sRed[4][12];

  // ---- routing data + B-fragment prefetch (stem + both layers) ----
  const int e0 = __builtin_amdgcn_readfirstlane(route_e[p]);
  const int e1 = __builtin_amdgcn_readfirstlane(route_e[256 + p]);
  const float gp0 = route_gate[p], gp1 = route_gate[256 + p];
  const int cp0 = route_cpre[p], cp1 = route_cpre[256 + p];
  const int Ce0 = route_Ce[e0], Ce1 = route_Ce[8 + e1];
  // col<8 mask keeps zero-padded D columns 8..15 out of GN stats / sums
  const float gate0 = (col < 8 && b * Ce0 + cp0 <= CAPV) ? gp0 : 0.f;
  const float gate1 = (col < 8 && b * Ce1 + cp1 <= CAPV) ? gp1 : 0.f;
  const int le0 = e0, le1 = 8 + e1;
  const bf16x8* sp = (const bf16x8*)stemPack;
  const bf16x8* bp0 = (const bf16x8*)(expPack + le0 * 1536);
  const bf16x8* bp1 = (const bf16x8*)(expPack + le1 * 1536);
  bf16x8 SB0 = sp[lane], SB1 = sp[64 + lane], SB2 = sp[128 + lane];
  bf16x8 B00 = bp0[lane], B01 = bp0[64 + lane], B02 = bp0[128 + lane];
  bf16x8 B10 = bp1[lane], B11 = bp1[64 + lane], B12 = bp1[128 + lane];

  // ---- phase 0: zero halo (block-shared) + own-token border ring ----
  {
    float4 z4 = {0.f, 0.f, 0.f, 0.f};
    float4* h4 = (float4*)&sH[0][0][0];  // 10*36*8*2B = 5760 B = 360 float4
#pragma unroll
    for (int i = 0; i < 2; ++i) {
      int idx = tid + i * 256;
      if (idx < 360) h4[idx] = z4;
    }
  }
  if (lane < 56) {  // sT ring: rows 0,9 (12 cols) + cols 0,9,10,11 (rows 1..8)
    int row, c2;
    if (lane < 12) { row = 0; c2 = lane; }
    else if (lane < 24) { row = 9; c2 = lane - 12; }
    else { int q = lane - 24; row = 1 + (q >> 2); int m = q & 3; c2 = (m == 0) ? 0 : 8 + m; }
    int4 z = {0, 0, 0, 0};
    *(int4*)&sT[w][row][c2][0] = z;
  }
  __syncthreads();

  // ---- halo fill: 3 x 10 x 34 region, fp32 coalesced read -> bf16 ch-last ----
  const int gy0 = hp * 8 - 1, gx0 = wq * 32 - 1;
#pragma unroll
  for (int k = 0; k < 4; ++k) {
    int i = tid + k * 256;
    if (i < 1020) {
      int ci = i / 340, rem = i - ci * 340;
      int r = rem / 34, c = rem - r * 34;
      int gy = gy0 + r, gx = gx0 + c;
      if (gy >= 0 && gy < 128 && gx >= 0 && gx < 128)
        sH[r][c][ci] = (__bf16)X[((b * 3 + ci) * 128 + gy) * 128 + gx];
    }
  }
  __syncthreads();

  // ---- stem conv via MFMA (3->8ch, K=96, BN scale folded into B) ----
  {
    const float bias = stem_bi[col & 7];
    f32x4 d0 = {0.f, 0.f, 0.f, 0.f}, d1 = d0, d2 = d0, d3 = d0;
#pragma unroll
    for (int c = 0; c < 3; ++c) {
      const __bf16* ab = &sH[ay + c][w * 8 + ax + gq][0];  // 16B-aligned
      bf16x8 A0 = *(const bf16x8*)(ab);          // rowgroup stride = 2 rows
      bf16x8 A1 = *(const bf16x8*)(ab + 576);    // 36*8*2 = 576 elems
      bf16x8 A2 = *(const bf16x8*)(ab + 1152);
      bf16x8 A3 = *(const bf16x8*)(ab + 1728);
      bf16x8 Bc = (c == 0) ? SB0 : (c == 1) ? SB1 : SB2;
      d0 = __builtin_amdgcn_mfma_f32_16x16x32_bf16(A0, Bc, d0, 0, 0, 0);
      d1 = __builtin_amdgcn_mfma_f32_16x16x32_bf16(A1, Bc, d1, 0, 0, 0);
      d2 = __builtin_amdgcn_mfma_f32_16x16x32_bf16(A2, Bc, d2, 0, 0, 0);
      d3 = __builtin_amdgcn_mfma_f32_16x16x32_bf16(A3, Bc, d3, 0, 0, 0);
    }
    if (col < 8) {
#pragma unroll
      for (int rg = 0; rg < 4; ++rg) {
        f32x4 dr = (rg == 0) ? d0 : (rg == 1) ? d1 : (rg == 2) ? d2 : d3;
#pragma unroll
        for (int r = 0; r < 4; ++r) {
          float t = silu_f(dr[r] + bias);
          sT[w][rg * 2 + dy_][dx_ + r][col] = (__bf16)t;
        }
      }
    }
  }
  // sT[w] is wave-private; in-wave DS ordering suffices (no barrier).

  const __bf16* abase = &sT[w][ay][ax + gq][0];
  const float bias0 = exp_b[le0 * 8 + (col & 7)];
  const float bias1 = exp_b[le1 * 8 + (col & 7)];
  const float sgs0 = gn_s[col & 7], sgb0 = gn_b[col & 7];

  float v1s, v1q;
  {
    // ---------- expert layer 0 ----------
    f32x4 a0 = {0.f, 0.f, 0.f, 0.f}, a1 = a0, a2 = a0, a3 = a0;
#pragma unroll
    for (int c = 0; c < 3; ++c) {
      bf16x8 A0 = *(const bf16x8*)(abase + (0 * 192 + c * 96));
      bf16x8 A1 = *(const bf16x8*)(abase + (1 * 192 + c * 96));
      bf16x8 A2 = *(const bf16x8*)(abase + (2 * 192 + c * 96));
      bf16x8 A3 = *(const bf16x8*)(abase + (3 * 192 + c * 96));
      bf16x8 Bc = (c == 0) ? B00 : (c == 1) ? B01 : B02;
      a0 = __builtin_amdgcn_mfma_f32_16x16x32_bf16(A0, Bc, a0, 0, 0, 0);
      a1 = __builtin_amdgcn_mfma_f32_16x16x32_bf16(A1, Bc, a1, 0, 0, 0);
      a2 = __builtin_amdgcn_mfma_f32_16x16x32_bf16(A2, Bc, a2, 0, 0, 0);
      a3 = __builtin_amdgcn_mfma_f32_16x16x32_bf16(A3, Bc, a3, 0, 0, 0);
    }
    float v[16];
    float s = 0.f, q = 0.f;
#pragma unroll
    for (int rg = 0; rg < 4; ++rg) {
      f32x4 ar = (rg == 0) ? a0 : (rg == 1) ? a1 : (rg == 2) ? a2 : a3;
#pragma unroll
      for (int r = 0; r < 4; ++r) {
        float t = silu_f(ar[r] + bias0) * gate0;
        v[rg * 4 + r] = t;
        s += t;
        q += t * t;
      }
    }
    s += __shfl_xor(s, 16, 64); q += __shfl_xor(q, 16, 64);
    s += __shfl_xor(s, 32, 64); q += __shfl_xor(q, 32, 64);
    s += __shfl_xor(s, 1, 64);  q += __shfl_xor(q, 1, 64);
    float mu = s * (1.f / 128.f);
    float var = q * (1.f / 128.f) - mu * mu;
    float inv = rsqrtf(var + 1e-5f);
    float sc2 = inv * sgs0;
    float bi2 = fmaf(-mu, sc2, sgb0);
    if (col < 8) {
#pragma unroll
      for (int rg = 0; rg < 4; ++rg)
#pragma unroll
        for (int r = 0; r < 4; ++r) {
          float n = fmaf(v[rg * 4 + r], sc2, bi2);
          sT[w][rg * 2 + dy_][dx_ + r][col] = (__bf16)n;
        }
    }
  }
  {
    // ---------- expert layer 1 ----------
    f32x4 a0 = {0.f, 0.f, 0.f, 0.f}, a1 = a0, a2 = a0, a3 = a0;
#pragma unroll
    for (int c = 0; c < 3; ++c) {
      bf16x8 A0 = *(const bf16x8*)(abase + (0 * 192 + c * 96));
      bf16x8 A1 = *(const bf16x8*)(abase + (1 * 192 + c * 96));
      bf16x8 A2 = *(const bf16x8*)(abase + (2 * 192 + c * 96));
      bf16x8 A3 = *(const bf16x8*)(abase + (3 * 192 + c * 96));
      bf16x8 Bc = (c == 0) ? B10 : (c == 1) ? B11 : B12;
      a0 = __builtin_amdgcn_mfma_f32_16x16x32_bf16(A0, Bc, a0, 0, 0, 0);
      a1 = __builtin_amdgcn_mfma_f32_16x16x32_bf16(A1, Bc, a1, 0, 0, 0);
      a2 = __builtin_amdgcn_mfma_f32_16x16x32_bf16(A2, Bc, a2, 0, 0, 0);
      a3 = __builtin_amdgcn_mfma_f32_16x16x32_bf16(A3, Bc, a3, 0, 0, 0);
    }
    float s = 0.f, q = 0.f;
#pragma unroll
    for (int rg = 0; rg < 4; ++rg) {
      f32x4 ar = (rg == 0) ? a0 : (rg == 1) ? a1 : (rg == 2) ? a2 : a3;
#pragma unroll
      for (int r = 0; r < 4; ++r) {
        float t = silu_f(ar[r] + bias1) * gate1;
        s += t;
        q += t * t;
      }
    }
    s += __shfl_xor(s, 16, 64); q += __shfl_xor(q, 16, 64);
    s += __shfl_xor(s, 32, 64); q += __shfl_xor(q, 32, 64);
    v1s = s;
    v1q = q + __shfl_xor(q, 1, 64);
  }

  if (lane < 8) sRed[w][lane] = v1s;                       // col==lane, gq==0
  if (lane < 8 && !(lane & 1)) sRed[w][8 + (lane >> 1)] = v1q;
  __syncthreads();
  if (tid < 12)
    blk_sums[(size_t)g * 12 + tid] =
        sRed[0][tid] + sRed[1][tid] + sRed[2][tid] + sRed[3][tid];
}

// ---------------- finish: per-image GN-folded pooling + MLP head ----------------
__global__ __launch_bounds__(64) void finish_kernel(
    const float* __restrict__ blk_sums,
    const float* __restrict__ gn_s, const float* __restrict__ gn_b,
    const float* __restrict__ w1, const float* __restrict__ b1,
    const float* __restrict__ w2, const float* __restrict__ b2,
    float* __restrict__ out) {
  const int b = blockIdx.x;
  const int lane = threadIdx.x;

  const float4* s4 = (const float4*)(blk_sums + (size_t)(b * 64 + lane) * 12);
  float4 a0 = s4[0], a1 = s4[1], a2 = s4[2];
  float l0[12] = {a0.x, a0.y, a0.z, a0.w, a1.x, a1.y, a1.z, a1.w,
                  a2.x, a2.y, a2.z, a2.w};
#pragma unroll
  for (int j = 0; j < 12; ++j) l0[j] = wave_sum64(l0[j]);

  float pooled[8];
#pragma unroll
  for (int c = 0; c < 8; ++c) {
    int gg = c >> 1;
    float mean_c = l0[c] * (1.f / 16384.f);
    float mug = (l0[2 * gg] + l0[2 * gg + 1]) * (1.f / 32768.f);
    float var = l0[8 + gg] * (1.f / 32768.f) - mug * mug;
    pooled[c] = fmaf((mean_c - mug) * rsqrtf(var + 1e-5f), gn_s[8 + c], gn_b[8 + c]);
  }

  __shared__ float sH1[32];
  if (lane < 32) {
    float h = b1[lane];
#pragma unroll
    for (int c = 0; c < 8; ++c) h = fmaf(pooled[c], w1[c * 32 + lane], h);
    float t = 0.7978845608028654f * fmaf(0.044715f * h * h, h, h);
    sH1[lane] = 0.5f * h * (1.f + tanhf(t));
  }
  __syncthreads();
  for (int o = lane; o < 100; o += 64) {
    float v = b2[o];
#pragma unroll
    for (int j = 0; j < 32; ++j) v = fmaf(sH1[j], w2[j * 100 + o], v);
    out[b * 100 + o] = v;
  }
}

extern "C" void kernel_launch(void* const* d_in, const int* in_sizes, int n_in,
                              void* d_out, int out_size, void* d_ws, size_t ws_size,
                              hipStream_t stream) {
  const float* X       = (const float*)d_in[0];
  const float* stem_w  = (const float*)d_in[1];
  const float* stem_sc = (const float*)d_in[2];
  const float* stem_bi = (const float*)d_in[3];
  const float* gate_w  = (const float*)d_in[4];
  const float* gate_b  = (const float*)d_in[5];
  const float* exp_w   = (const float*)d_in[6];
  const float* exp_b   = (const float*)d_in[7];
  const float* gn_s    = (const float*)d_in[8];
  const float* gn_b    = (const float*)d_in[9];
  const float* w1      = (const float*)d_in[10];
  const float* b1      = (const float*)d_in[11];
  const float* w2      = (const float*)d_in[12];
  const float* b2      = (const float*)d_in[13];
  float* out = (float*)d_out;

  char* ws = (char*)d_ws;
  int* route_e      = (int*)(ws + 0);          // 512 ints
  int* route_cpre   = (int*)(ws + 2048);       // 512 ints
  int* route_Ce     = (int*)(ws + 4096);       // 16 ints
  float* route_gate = (float*)(ws + 4160);     // 512 floats
  __bf16* stemPack  = (__bf16*)(ws + 8192);    // 1536 bf16 (3 KiB)
  __bf16* expPack   = (__bf16*)(ws + 16384);   // 16*1536 bf16 (48 KiB)
  float* blk_sums   = (float*)(ws + 65536);    // 4096*12 floats (192 KiB)

  routing_kernel<<<17, 256, 0, stream>>>(gate_w, gate_b, stem_w, stem_sc, exp_w,
                                         route_e, route_gate, route_cpre,
                                         route_Ce, stemPack, expPack, out + 6400);
  token_kernel<<<4096, 256, 0, stream>>>(X, stemPack, stem_bi, expPack, exp_b,
                                         gn_s, gn_b, route_e, route_gate,
                                         route_cpre, route_Ce, blk_sums);
  finish_kernel<<<64, 64, 0, stream>>>(blk_sums, gn_s, gn_b, w1, b1, w2, b2,
                                       out);
}